// Round 1
// baseline (15625.008 us; speedup 1.0000x reference)
//
#include <hip/hip_runtime.h>
#include <hip/hip_bf16.h>

// =====================================================================
// PlantLSTM: 2-layer LSTM (H=256) + FC head, B=256, T=512, autoregressive
// pv feedback. Design (R1):
//  - 128 persistent workgroups x 256 threads, each owns 2 batch elements
//    for all 512 steps (batch lanes independent -> no inter-block sync).
//  - Weights converted once per launch to f16, transposed+gate-interleaved
//    into d_ws: layout [k2][unit][4 gates] as half2 -> one coalesced
//    dwordx4 per thread per k2 feeds all 4 gates (i,f,g,o) of its unit.
//  - emb contribution to L0 gates is t-invariant -> folded into per-batch
//    bias registers at init (drops K from 328 to 296).
//  - Inner product via v_dot2_f32_f16 (f32 accumulate), activations fp32.
//  - 16-deep register double-buffer on the weight stream to hide L2 latency.
// =====================================================================

#define B_TOT   256
#define T_STEPS 512
#define NIN     32
#define NOUT    8
#define HDIM    256
#define EMBD    32

#define BPG   2              // batch elements per workgroup
#define NBLK  (B_TOT / BPG)  // 128 workgroups
#define NTHR  256

// L0 input: [x(32) | pv(8) | h0(256)] -> K=296 -> K2=148, padded to 160
#define K2_0      160
#define K2_0_REAL 148
#define NCH0      10   // 160/16 chunks
// L1 input: [h0(256) | h1(256)] -> K=512 -> K2=256
#define K2_1      256
#define NCH1      16   // 256/16 chunks

// d_ws layout (bytes); total 1,771,520
#define WT0_OFF   0u
#define WT0_BYTES (K2_0 * HDIM * 4u * 4u)    // 655360
#define WT1_OFF   (WT0_OFF + WT0_BYTES)
#define WT1_BYTES (K2_1 * HDIM * 4u * 4u)    // 1048576
#define FC1_OFF   (WT1_OFF + WT1_BYTES)
#define FC1_BYTES (128u * 128u * 4u)         // 65536
#define FC2_OFF   (FC1_OFF + FC1_BYTES)
#define FC2_BYTES (64u * 8u * 4u)            // 2048

typedef _Float16 h2 __attribute__((ext_vector_type(2)));

#if __has_builtin(__builtin_amdgcn_fdot2)
#define FDOT2(a, b, c) __builtin_amdgcn_fdot2((a), (b), (c), false)
#else
#define FDOT2(a, b, c) ((c) + (float)(a).x * (float)(b).x + (float)(a).y * (float)(b).y)
#endif

__device__ __forceinline__ float sigm(float x) {
    return 1.0f / (1.0f + __expf(-x));
}
__device__ __forceinline__ float tanh_fast(float x) {
    // 1 - 2/(e^{2x}+1): safe at +/-inf (no inf/inf)
    float e = __expf(2.0f * x);
    return 1.0f - 2.0f / (e + 1.0f);
}

// ------------------------- prep kernels -------------------------
// wt0: half2 index (k2<<10)|(u<<2)|g ; g row = g*256+u of [W_ih0 cols 0..39 | W_hh0]
__global__ void prep_wt0(const float* __restrict__ Wih0,
                         const float* __restrict__ Whh0,
                         h2* __restrict__ wt0) {
    int hidx = blockIdx.x * blockDim.x + threadIdx.x;
    if (hidx >= K2_0 * 1024) return;
    int g = hidx & 3, uu = (hidx >> 2) & 255, k2 = hidx >> 10;
    h2 r = {(_Float16)0.0f, (_Float16)0.0f};
    if (k2 < K2_0_REAL) {
        int row = g * 256 + uu;
        int k = 2 * k2;
        float v0 = (k < 40)     ? Wih0[row * 72 + k]     : Whh0[row * 256 + (k - 40)];
        float v1 = (k + 1 < 40) ? Wih0[row * 72 + k + 1] : Whh0[row * 256 + (k + 1 - 40)];
        r.x = (_Float16)v0;
        r.y = (_Float16)v1;
    }
    wt0[hidx] = r;
}

__global__ void prep_wt1(const float* __restrict__ Wih1,
                         const float* __restrict__ Whh1,
                         h2* __restrict__ wt1) {
    int hidx = blockIdx.x * blockDim.x + threadIdx.x;
    if (hidx >= K2_1 * 1024) return;
    int g = hidx & 3, uu = (hidx >> 2) & 255, k2 = hidx >> 10;
    int row = g * 256 + uu;
    int k = 2 * k2;
    float v0 = (k < 256)     ? Wih1[row * 256 + k]           : Whh1[row * 256 + (k - 256)];
    float v1 = (k + 1 < 256) ? Wih1[row * 256 + k + 1]       : Whh1[row * 256 + (k + 1 - 256)];
    h2 r;
    r.x = (_Float16)v0;
    r.y = (_Float16)v1;
    wt1[hidx] = r;
}

__global__ void prep_fc(const float* __restrict__ fc1w,
                        const float* __restrict__ fc2w,
                        h2* __restrict__ f1t,
                        h2* __restrict__ f2t) {
    int hidx = blockIdx.x * blockDim.x + threadIdx.x;
    if (hidx < 16384) {
        int r = hidx & 127, k2 = hidx >> 7;
        h2 v;
        v.x = (_Float16)fc1w[r * 256 + 2 * k2];
        v.y = (_Float16)fc1w[r * 256 + 2 * k2 + 1];
        f1t[hidx] = v;
    } else if (hidx < 16384 + 512) {
        int hi = hidx - 16384;
        int j = hi & 7, k2 = hi >> 3;
        h2 v;
        v.x = (_Float16)fc2w[j * 128 + 2 * k2];
        v.y = (_Float16)fc2w[j * 128 + 2 * k2 + 1];
        f2t[hi] = v;
    }
}

// ------------------------- main kernel helpers -------------------------
__device__ __forceinline__ void load16(float4 (&buf)[16],
                                       const float4* __restrict__ wt,
                                       int k2b, int u) {
#pragma unroll
    for (int j = 0; j < 16; ++j) buf[j] = wt[(k2b + j) * 256 + u];
}

template <int S>
__device__ __forceinline__ void comp16(const float4 (&buf)[16],
                                       const h2* xt, int k2b,
                                       float (&acc)[4][BPG]) {
#pragma unroll
    for (int j = 0; j < 16; ++j) {
        h2 w0 = __builtin_bit_cast(h2, buf[j].x);
        h2 w1 = __builtin_bit_cast(h2, buf[j].y);
        h2 w2 = __builtin_bit_cast(h2, buf[j].z);
        h2 w3 = __builtin_bit_cast(h2, buf[j].w);
#pragma unroll
        for (int i = 0; i < BPG; ++i) {
            h2 xv = xt[i * S + k2b + j];
            acc[0][i] = FDOT2(w0, xv, acc[0][i]);
            acc[1][i] = FDOT2(w1, xv, acc[1][i]);
            acc[2][i] = FDOT2(w2, xv, acc[2][i]);
            acc[3][i] = FDOT2(w3, xv, acc[3][i]);
        }
    }
}

// double-buffered weight stream: 16 float4 (one chunk) in flight ahead
template <int S>
__device__ __forceinline__ void matvec_pipe(const float4* __restrict__ wt,
                                            const h2* xt, int NCH, int u,
                                            float (&acc)[4][BPG]) {
    float4 A[16], Bb[16];
    load16(A, wt, 0, u);
    int c = 0;
    for (; c + 2 < NCH; c += 2) {
        load16(Bb, wt, (c + 1) * 16, u);
        comp16<S>(A, xt, c * 16, acc);
        load16(A, wt, (c + 2) * 16, u);
        comp16<S>(Bb, xt, (c + 1) * 16, acc);
    }
    if (NCH & 1) {
        comp16<S>(A, xt, (NCH - 1) * 16, acc);
    } else {
        load16(Bb, wt, (NCH - 1) * 16, u);
        comp16<S>(A, xt, (NCH - 2) * 16, acc);
        comp16<S>(Bb, xt, (NCH - 1) * 16, acc);
    }
}

// ------------------------- main kernel -------------------------
__global__ __launch_bounds__(NTHR, 1) void lstm_main(
    const float* __restrict__ x_cv, const float* __restrict__ pv_init,
    const int* __restrict__ scen, const float* __restrict__ emb_table,
    const float* __restrict__ Wih0, const float* __restrict__ b_ih0,
    const float* __restrict__ b_hh0, const float* __restrict__ b_ih1,
    const float* __restrict__ b_hh1, const float* __restrict__ fc1_b,
    const float* __restrict__ fc2_b, const float4* __restrict__ wt0,
    const float4* __restrict__ wt1, const h2* __restrict__ fc1t,
    const h2* __restrict__ fc2t, float* __restrict__ out) {
    __shared__ h2 xt0[BPG][K2_0];   // L0 input  [x | pv | h0] as half2
    __shared__ h2 xt1[BPG][K2_1];   // L1 input  [h0 | h1]    as half2
    __shared__ h2 fch[BPG][64];     // FC2 input (relu fc1) as half2
    __shared__ float h0f[BPG][HDIM];
    __shared__ float h1f[BPG][HDIM];
    __shared__ float fc1o[BPG][128];
    __shared__ float pvf[BPG][NOUT];
    __shared__ float embs[BPG][EMBD];

    const int tid = threadIdx.x;
    const int u = tid;                 // hidden unit owned by this thread
    const int b0 = blockIdx.x * BPG;   // first batch element of this WG

    // ---- init: zeros, pv_init, emb staging ----
    {
        h2 z = {(_Float16)0.0f, (_Float16)0.0f};
        {   // xt0 h0-part zero (k2 20..147): 256 tasks
            int i = tid >> 7, p = tid & 127;
            xt0[i][20 + p] = z;
        }
        for (int idx = tid; idx < BPG * K2_1; idx += NTHR) {  // xt1 all zero
            int i = idx >> 8, p = idx & 255;
            xt1[i][p] = z;
        }
        if (tid < BPG * 12) {  // xt0 pad k2 148..159
            int i = tid / 12, p = tid % 12;
            xt0[i][K2_0_REAL + p] = z;
        }
        if (tid < BPG * NOUT) {
            int i = tid >> 3, j = tid & 7;
            pvf[i][j] = pv_init[(b0 + i) * NOUT + j];
        }
        if (tid < BPG * EMBD) {
            int i = tid >> 5, kk = tid & 31;
            embs[i][kk] = emb_table[scen[b0 + i] * EMBD + kk];
        }
    }
    __syncthreads();

    // ---- fold emb into per-batch L0 bias; load L1 bias ----
    float bias0[4][BPG], bias1g[4];
#pragma unroll
    for (int g = 0; g < 4; ++g) {
        const int row = g * 256 + u;
        bias1g[g] = b_ih1[row] + b_hh1[row];
        float s0 = b_ih0[row] + b_hh0[row];
        float s1 = s0;
        for (int kk = 0; kk < EMBD; ++kk) {
            float w = Wih0[row * 72 + 40 + kk];
            s0 += embs[0][kk] * w;
            s1 += embs[1][kk] * w;
        }
        bias0[g][0] = s0;
        bias0[g][1] = s1;
    }

    const float fc1bias = fc1_b[tid & 127];
    float fc2bias = 0.0f;
    float* outp = nullptr;
    if (tid < BPG * NOUT) {
        int j = tid & 7, i = tid >> 3;
        fc2bias = fc2_b[j];
        outp = out + ((size_t)(b0 + i) * T_STEPS) * NOUT + j;
    }

    float c0v[BPG] = {0.0f, 0.0f};
    float c1v[BPG] = {0.0f, 0.0f};

    for (int t = 0; t < T_STEPS; ++t) {
        // P1: fill x and pv parts of xt0 (k2 0..19)
        if (tid < BPG * 20) {
            int i = tid / 20, k2l = tid % 20;
            h2 v;
            if (k2l < 16) {
                const float* xp =
                    x_cv + ((size_t)(b0 + i) * T_STEPS + t) * NIN + 2 * k2l;
                v.x = (_Float16)xp[0];
                v.y = (_Float16)xp[1];
            } else {
                v.x = (_Float16)pvf[i][2 * (k2l - 16)];
                v.y = (_Float16)pvf[i][2 * (k2l - 16) + 1];
            }
            xt0[i][k2l] = v;
        }
        __syncthreads();

        // P2: layer-0 gates
        float acc[4][BPG];
#pragma unroll
        for (int g = 0; g < 4; ++g)
#pragma unroll
            for (int i = 0; i < BPG; ++i) acc[g][i] = bias0[g][i];
        matvec_pipe<K2_0>(wt0, &xt0[0][0], NCH0, u, acc);

        // P3: layer-0 elementwise (thread owns all 4 gates of unit u)
#pragma unroll
        for (int i = 0; i < BPG; ++i) {
            float ig = sigm(acc[0][i]);
            float fg = sigm(acc[1][i]);
            float gg = tanh_fast(acc[2][i]);
            float og = sigm(acc[3][i]);
            float cn = fg * c0v[i] + ig * gg;
            c0v[i] = cn;
            h0f[i][u] = og * tanh_fast(cn);
        }
        __syncthreads();

        // P3b: pack h0 pairs -> xt0 h-part (next step) and xt1 h0-part (this step)
        {
            int i = tid >> 7, p = tid & 127;
            h2 v;
            v.x = (_Float16)h0f[i][2 * p];
            v.y = (_Float16)h0f[i][2 * p + 1];
            xt0[i][20 + p] = v;
            xt1[i][p] = v;
        }
        __syncthreads();

        // P4: layer-1 gates
#pragma unroll
        for (int g = 0; g < 4; ++g)
#pragma unroll
            for (int i = 0; i < BPG; ++i) acc[g][i] = bias1g[g];
        matvec_pipe<K2_1>(wt1, &xt1[0][0], NCH1, u, acc);

        // P5: layer-1 elementwise
#pragma unroll
        for (int i = 0; i < BPG; ++i) {
            float ig = sigm(acc[0][i]);
            float fg = sigm(acc[1][i]);
            float gg = tanh_fast(acc[2][i]);
            float og = sigm(acc[3][i]);
            float cn = fg * c1v[i] + ig * gg;
            c1v[i] = cn;
            h1f[i][u] = og * tanh_fast(cn);
        }
        __syncthreads();

        // P5b: pack h1 pairs -> xt1 h1-part (used by FC1 now, L1 next step)
        {
            int i = tid >> 7, p = tid & 127;
            h2 v;
            v.x = (_Float16)h1f[i][2 * p];
            v.y = (_Float16)h1f[i][2 * p + 1];
            xt1[i][128 + p] = v;
        }
        __syncthreads();

        // P6: FC1 (+ReLU). 256 tasks: r = tid&127, batch i = tid>>7
        {
            int r = tid & 127, i = tid >> 7;
            float a = fc1bias;
            const h2* xrow = &xt1[i][128];
#pragma unroll 8
            for (int k2 = 0; k2 < 128; ++k2)
                a = FDOT2(fc1t[k2 * 128 + r], xrow[k2], a);
            fc1o[i][r] = fmaxf(a, 0.0f);
        }
        __syncthreads();

        // P6b: pack fc1 pairs
        if (tid < BPG * 64) {
            int i = tid >> 6, p = tid & 63;
            h2 v;
            v.x = (_Float16)fc1o[i][2 * p];
            v.y = (_Float16)fc1o[i][2 * p + 1];
            fch[i][p] = v;
        }
        __syncthreads();

        // P7: FC2 -> output + pv feedback
        if (tid < BPG * NOUT) {
            int j = tid & 7, i = tid >> 3;
            float a = fc2bias;
#pragma unroll 8
            for (int k2 = 0; k2 < 64; ++k2)
                a = FDOT2(fc2t[k2 * 8 + j], fch[i][k2], a);
            outp[(size_t)t * NOUT] = a;
            pvf[i][j] = a;
        }
        __syncthreads();
    }
}

// ------------------------- launch -------------------------
extern "C" void kernel_launch(void* const* d_in, const int* in_sizes, int n_in,
                              void* d_out, int out_size, void* d_ws,
                              size_t ws_size, hipStream_t stream) {
    const float* x_cv = (const float*)d_in[0];
    const float* pv_init = (const float*)d_in[1];
    const int* scen = (const int*)d_in[2];
    const float* embt = (const float*)d_in[3];
    const float* Wih0 = (const float*)d_in[4];
    const float* Whh0 = (const float*)d_in[5];
    const float* bih0 = (const float*)d_in[6];
    const float* bhh0 = (const float*)d_in[7];
    const float* Wih1 = (const float*)d_in[8];
    const float* Whh1 = (const float*)d_in[9];
    const float* bih1 = (const float*)d_in[10];
    const float* bhh1 = (const float*)d_in[11];
    const float* fc1w = (const float*)d_in[12];
    const float* fc1b = (const float*)d_in[13];
    const float* fc2w = (const float*)d_in[14];
    const float* fc2b = (const float*)d_in[15];

    char* ws = (char*)d_ws;
    h2* wt0 = (h2*)(ws + WT0_OFF);
    h2* wt1 = (h2*)(ws + WT1_OFF);
    h2* f1t = (h2*)(ws + FC1_OFF);
    h2* f2t = (h2*)(ws + FC2_OFF);

    prep_wt0<<<(K2_0 * 1024) / 256, 256, 0, stream>>>(Wih0, Whh0, wt0);
    prep_wt1<<<(K2_1 * 1024) / 256, 256, 0, stream>>>(Wih1, Whh1, wt1);
    prep_fc<<<66, 256, 0, stream>>>(fc1w, fc2w, f1t, f2t);

    lstm_main<<<NBLK, NTHR, 0, stream>>>(
        x_cv, pv_init, scen, embt, Wih0, bih0, bhh0, bih1, bhh1, fc1b, fc2b,
        (const float4*)wt0, (const float4*)wt1, f1t, f2t, (float*)d_out);
}